// Round 7
// baseline (191.439 us; speedup 1.0000x reference)
//
#include <hip/hip_runtime.h>

// Match numpy f32 semantics: no FMA contraction anywhere in this TU.
#pragma clang fp contract(off)

#define VWD 96
#define NVERT 2048
#define NFAC 512
#define NBATCH 8
#define NSLAB 3456          // 144 columns x 24 z-slabs of 8x8x4 voxels
#define RECF 16             // floats per facet body record
#define CULC 26             // cull components (SoA)
#define NUNIT (NBATCH * NSLAB)   // 27648 slab-units
#define VOXBLK 4096              // persistent grid: 16 blocks/CU x 256 CU
#define NWAVE (VOXBLK * 2)       // 8192 waves, 3-4 units each

// SoA cull addressing: component c, batch b, facet f
#define CUL(c, b, f) cul[(size_t)(c) * (NBATCH * NFAC) + (size_t)(b) * NFAC + (f)]

// ---------------------------------------------------------------------------
// Kernel 1: per-batch facet precompute, ordered by |det| descending via a
// ONE-BARRIER rank sort. Body records SIGN-FOLDED: det<0 => negate A,det
// (IEEE negation commutes exactly through mul/add/div).
//   body[b][s][16] : det,v3x,v3y,v3z, A00..A22, dhi, mhi, pad
// Per-plane containment delta D_i = -(M + 2E + 2e-3): slab center passing
// d_i <= D_i for all 4 planes => whole slab definitely inside (convexity;
// plane row and adjugate row are both 2*face-area so |det| cancels in
// barycentric units; degenerate facets cannot pass).
// ---------------------------------------------------------------------------
__global__ __launch_bounds__(512) void precompute_kernel(
    const float* __restrict__ vertices,
    const int*   __restrict__ facets,
    float*       __restrict__ cul,
    float*       __restrict__ body)
{
    __shared__ unsigned skey[NFAC];
    const int b = blockIdx.x;
    const int j = threadIdx.x;          // one facet per thread
    const float* vb = vertices + (size_t)b * NVERT * 3;

    int4 fi = ((const int4*)facets)[b * NFAC + j];
    float x0 = vb[3*fi.x+0], y0 = vb[3*fi.x+1], z0 = vb[3*fi.x+2];
    float x1 = vb[3*fi.y+0], y1 = vb[3*fi.y+1], z1 = vb[3*fi.y+2];
    float x2 = vb[3*fi.z+0], y2 = vb[3*fi.z+1], z2 = vb[3*fi.z+2];
    float x3 = vb[3*fi.w+0], y3 = vb[3*fi.w+1], z3 = vb[3*fi.w+2];
    float a  = x0-x3, bb = x1-x3, c  = x2-x3;
    float d  = y0-y3, e  = y1-y3, f  = y2-y3;
    float g  = z0-z3, h  = z1-z3, ii = z2-z3;
    float A00 = e*ii - f*h,  A01 = c*h  - bb*ii, A02 = bb*f - c*e;
    float A10 = f*g  - d*ii, A11 = a*ii - c*g,   A12 = c*d  - a*f;
    float A20 = d*h  - e*g,  A21 = bb*g - a*h,   A22 = a*e  - bb*d;
    float det = a*(e*ii - f*h) - bb*(d*ii - f*g) + c*(d*h - e*g);
    if (det < 0.0f) {   // sign-fold (exact)
        det = -det;
        A00 = -A00; A01 = -A01; A02 = -A02;
        A10 = -A10; A11 = -A11; A12 = -A12;
        A20 = -A20; A21 = -A21; A22 = -A22;
    }
    unsigned myk = ~__float_as_uint(det);   // ascending key == descending |det|
    skey[j] = myk;
    __syncthreads();

    // rank = #{k : key_k < myk or (key_k == myk and k < j)}  -> unique slot
    int rank = 0;
    const uint4* sk4 = (const uint4*)skey;
    for (int k0 = 0; k0 < NFAC; k0 += 4) {
        uint4 kk = sk4[k0 >> 2];
        rank += (kk.x < myk) + ((kk.x == myk) & (k0 + 0 < j));
        rank += (kk.y < myk) + ((kk.y == myk) & (k0 + 1 < j));
        rank += (kk.z < myk) + ((kk.z == myk) & (k0 + 2 < j));
        rank += (kk.w < myk) + ((kk.w == myk) & (k0 + 3 < j));
    }

    CUL(0, b, rank) = fminf(fminf(x0,x1),fminf(x2,x3)) - 1e-4f;
    CUL(1, b, rank) = fminf(fminf(y0,y1),fminf(y2,y3)) - 1e-4f;
    CUL(2, b, rank) = fminf(fminf(z0,z1),fminf(z2,z3)) - 1e-4f;
    CUL(3, b, rank) = fmaxf(fmaxf(x0,x1),fmaxf(x2,x3)) + 1e-4f;
    CUL(4, b, rank) = fmaxf(fmaxf(y0,y1),fmaxf(y2,y3)) + 1e-4f;
    CUL(5, b, rank) = fmaxf(fmaxf(z0,z1),fmaxf(z2,z3)) + 1e-4f;

    // 4 outward face planes, margin-inflated, slab half-extents folded:
    // overlap test:      dot(n, slab_center) - rhs <= 0   (conservative)
    // containment test:  dot(n, slab_center) - rhs <= D   (definite)
    const float HX = 7.0f/96.0f, HZ = 3.0f/96.0f;
    auto plane = [&](float pax, float pay, float paz,
                     float pbx, float pby, float pbz,
                     float pcx, float pcy, float pcz,
                     float pox, float poy, float poz, int base, int pi) {
        float e1x = pbx-pax, e1y = pby-pay, e1z = pbz-paz;
        float e2x = pcx-pax, e2y = pcy-pay, e2z = pcz-paz;
        float nx = e1y*e2z - e1z*e2y;
        float ny = e1z*e2x - e1x*e2z;
        float nz = e1x*e2y - e1y*e2x;
        float sdot = nx*(pox-pax) + ny*(poy-pay) + nz*(poz-paz);
        if (sdot > 0.0f) { nx=-nx; ny=-ny; nz=-nz; sdot=-sdot; }
        float dpl = nx*pax + ny*pay + nz*paz;
        float n1s = fabsf(nx)+fabsf(ny)+fabsf(nz);
        float M = 1e-4f*(-sdot) + 1e-4f*n1s + 1e-4f;
        float E = fabsf(nx)*HX + fabsf(ny)*HX + fabsf(nz)*HZ;
        float rhs = dpl + M + E;
        CUL(base+0, b, rank) = nx;
        CUL(base+1, b, rank) = ny;
        CUL(base+2, b, rank) = nz;
        CUL(base+3, b, rank) = rhs;
        CUL(22+pi, b, rank) = -(M + 2.0f*E + 2e-3f);   // containment delta
    };
    plane(x1,y1,z1, x2,y2,z2, x3,y3,z3, x0,y0,z0, 6, 0);    // opposite v0
    plane(x0,y0,z0, x2,y2,z2, x3,y3,z3, x1,y1,z1, 10, 1);   // opposite v1
    plane(x0,y0,z0, x1,y1,z1, x3,y3,z3, x2,y2,z2, 14, 2);   // opposite v2
    plane(x0,y0,z0, x1,y1,z1, x2,y2,z2, x3,y3,z3, 18, 3);   // opposite v3

    float* bo = body + ((size_t)b * NFAC + rank) * RECF;
    bo[0]  = det; bo[1]  = x3;  bo[2]  = y3;  bo[3]  = z3;
    bo[4]  = A00; bo[5]  = A01; bo[6]  = A02; bo[7]  = A10;
    bo[8]  = A11; bo[9]  = A12; bo[10] = A20; bo[11] = A21;
    bo[12] = A22;
    bo[13] = det * (1.0f - 1e-5f) - 1e-25f;   // dhi
    bo[14] = det * (1.0f + 1e-5f) + 1e-25f;   // mhi
    bo[15] = 0.0f;
}

// ---------------------------------------------------------------------------
// Kernel 2: per-slab 512-bit facet mask + per-slab "fully contained" flag.
// One block per (batch, x-y column); facet-per-lane, cull record loaded ONCE
// (SoA, coalesced), 24 z-slabs via incremental plane dots (error ~1e-4 <<
// margins folded into rhs / delta).
// ---------------------------------------------------------------------------
__global__ __launch_bounds__(512) void mask_kernel(
    const float* __restrict__ cul,
    unsigned long long* __restrict__ masks,
    unsigned* __restrict__ fullmask)
{
    __shared__ unsigned fullbits;
    const int col = blockIdx.x;           // 0..143 = sx*12+sy
    const int b   = blockIdx.y;
    const int f   = threadIdx.x;          // facet (sorted order)
    const int w   = threadIdx.x >> 6;
    if (threadIdx.x == 0) fullbits = 0u;
    __syncthreads();
    float bminx=CUL(0,b,f), bminy=CUL(1,b,f), bminz=CUL(2,b,f);
    float bmaxx=CUL(3,b,f), bmaxy=CUL(4,b,f), bmaxz=CUL(5,b,f);
    float n0x=CUL(6,b,f),  n0y=CUL(7,b,f),  n0z=CUL(8,b,f),  r0=CUL(9,b,f);
    float n1x=CUL(10,b,f), n1y=CUL(11,b,f), n1z=CUL(12,b,f), r1=CUL(13,b,f);
    float n2x=CUL(14,b,f), n2y=CUL(15,b,f), n2z=CUL(16,b,f), r2=CUL(17,b,f);
    float n3x=CUL(18,b,f), n3y=CUL(19,b,f), n3z=CUL(20,b,f), r3=CUL(21,b,f);
    float D0=CUL(22,b,f), D1=CUL(23,b,f), D2=CUL(24,b,f), D3=CUL(25,b,f);

    const int sx = col / 12, sy = col % 12;
    const float cx = (float)(16*sx + 8 - VWD) / 96.0f;
    const float cy = (float)(16*sy + 8 - VWD) / 96.0f;
    const float colminx = (float)(16*sx + 1  - VWD) / 96.0f;
    const float colmaxx = (float)(16*sx + 15 - VWD) / 96.0f;
    const float colminy = (float)(16*sy + 1  - VWD) / 96.0f;
    const float colmaxy = (float)(16*sy + 15 - VWD) / 96.0f;
    const bool ovxy = (bminx <= colmaxx) & (bmaxx >= colminx) &
                      (bminy <= colmaxy) & (bmaxy >= colminy);

    const float cz0   = (float)(4 - VWD) / 96.0f;   // z-center of slab sz=0
    const float stepc = 8.0f / 96.0f;
    float d0 = n0x*cx + n0y*cy + n0z*cz0 - r0;  float s0 = n0z*stepc;
    float d1 = n1x*cx + n1y*cy + n1z*cz0 - r1;  float s1 = n1z*stepc;
    float d2 = n2x*cx + n2y*cy + n2z*cz0 - r2;  float s2 = n2z*stepc;
    float d3 = n3x*cx + n3y*cy + n3z*cz0 - r3;  float s3 = n3z*stepc;
    float zlo = (float)(1 - VWD) / 96.0f;
    float zhi = (float)(7 - VWD) / 96.0f;

    unsigned fullw = 0u;
    unsigned long long* mp = masks + ((size_t)b * NSLAB + (size_t)col * 24) * 8 + w;
#pragma unroll 4
    for (int sz = 0; sz < 24; ++sz) {
        bool ov = ovxy & (bminz <= zhi) & (bmaxz >= zlo) &
                  (d0 <= 0.0f) & (d1 <= 0.0f) & (d2 <= 0.0f) & (d3 <= 0.0f);
        bool fullv = (d0 <= D0) & (d1 <= D1) & (d2 <= D2) & (d3 <= D3);
        unsigned long long bal = __ballot((int)ov);
        if ((threadIdx.x & 63) == 0) mp[(size_t)sz * 8] = bal;
        if (__ballot((int)fullv) != 0ull) fullw |= (1u << sz);
        d0 += s0; d1 += s1; d2 += s2; d3 += s3;
        zlo += stepc; zhi += stepc;
    }
    if ((threadIdx.x & 63) == 0 && fullw) atomicOr(&fullbits, fullw);
    __syncthreads();
    if (threadIdx.x == 0) fullmask[b * 144 + col] = fullbits;
}

// Facet body record in wave-uniform (SGPR) registers.
struct Rec {
    float det, v3x, v3y, v3z;
    float A00, A01, A02, A10, A11, A12, A20, A21, A22;
    float dhi, mhi;
};

__device__ __forceinline__ void load_rec(Rec& r, const float* __restrict__ bo)
{
    float4 q0 = *(const float4*)(bo + 0);
    float4 q1 = *(const float4*)(bo + 4);
    float4 q2 = *(const float4*)(bo + 8);
    float4 q3 = *(const float4*)(bo + 12);
    r.det = q0.x; r.v3x = q0.y; r.v3y = q0.z; r.v3z = q0.w;
    r.A00 = q1.x; r.A01 = q1.y; r.A02 = q1.z; r.A10 = q1.w;
    r.A11 = q2.x; r.A12 = q2.y; r.A20 = q2.z; r.A21 = q2.w;
    r.A22 = q3.x; r.dhi = q3.y; r.mhi = q3.z;
}

// Scalarize a wave-uniform 64-bit value (keeps the candidate cursor on SALU
// and record loads as s_load; R5 lesson: losing this ballooned VGPR 20->52
// and turned record loads into per-lane vector loads).
__device__ __forceinline__ unsigned long long rfl64(unsigned long long v)
{
    unsigned lo = __builtin_amdgcn_readfirstlane((unsigned)v);
    unsigned hi = __builtin_amdgcn_readfirstlane((unsigned)(v >> 32));
    return ((unsigned long long)hi << 32) | lo;
}

// ---------------------------------------------------------------------------
// Per-candidate exact test on a register-resident record. Numerators
// bit-identical to ref; exact l_i>=0 sign test; det-relative shell on the
// sum; ONE __any branch per candidate guards the (rare) exact-division path.
// ---------------------------------------------------------------------------
__device__ __forceinline__ void facet_test_reg(
    const Rec& rr,
    float px, float py, float pz0, float pz1, float pz2, float pz3,
    unsigned& fnd)
{
    float dx = px - rr.v3x, dy = py - rr.v3y;
    // ref-exact partials (left-assoc, contract off)
    float p0 = rr.A00*dx + rr.A01*dy;
    float p1 = rr.A10*dx + rr.A11*dy;
    float p2 = rr.A20*dx + rr.A21*dy;
    float dzk0 = pz0 - rr.v3z, dzk1 = pz1 - rr.v3z;
    float dzk2 = pz2 - rr.v3z, dzk3 = pz3 - rr.v3z;
    unsigned need = 0u;   // bit k: lane in shell, must run exact path
#pragma unroll
    for (int k = 0; k < 4; ++k) {
        float dzk = (k == 0) ? dzk0 : (k == 1) ? dzk1
                  : (k == 2) ? dzk2 : dzk3;
        float n0 = p0 + rr.A02*dzk;
        float n1 = p1 + rr.A12*dzk;
        float n2 = p2 + rr.A22*dzk;
        float sm = (n0 + n1) + n2;
        float mn = fminf(fminf(n0, n1), n2);   // v_min3_f32
        bool ge0 = (mn >= 0.0f);               // EXACT l_i>=0 test
        bool def = ge0 & (sm <= rr.dhi);
        bool may = ge0 & (sm <= rr.mhi);
        if (may & !def & !((fnd >> k) & 1u)) need |= (1u << k);
        if (def) fnd |= (1u << k);
    }
    if (__any(need != 0u)) {
#pragma unroll
        for (int k = 0; k < 4; ++k) {
            float dzk = (k == 0) ? dzk0 : (k == 1) ? dzk1
                      : (k == 2) ? dzk2 : dzk3;
            float n0 = p0 + rr.A02*dzk;
            float n1 = p1 + rr.A12*dzk;
            float n2 = p2 + rr.A22*dzk;
            float l0 = n0 / rr.det;
            float l1 = n1 / rr.det;
            float l2 = n2 / rr.det;
            float l3 = 1.0f - ((l0 + l1) + l2);
            bool inside = (l0 >= 0.0f) & (l0 <= 1.0f) &
                          (l1 >= 0.0f) & (l1 <= 1.0f) &
                          (l2 >= 0.0f) & (l2 <= 1.0f) &
                          (l3 >= 0.0f) & (l3 <= 1.0f);
            if (((need >> k) & 1u) & inside) fnd |= (1u << k);
        }
    }
}

// ---------------------------------------------------------------------------
// Kernel 3 (PERSISTENT, R7): 4096 blocks x 128 thr = 8192 waves, launched
// ONCE (16 blocks/CU fills the workgroup slots in a single CP pass). Each
// wave serially processes 3-4 CONTIGUOUS slab-units (b,col,sz) — contiguity
// keeps 64B out-sectors wave-local. R6 lesson: every prior lean variant
// (13-28k blocks x ~1.5us) retired blocks at ~200-400/us = command-processor
// dispatch-rate bound (occupancy 26-40%, VALU ~50% at VGPR 20). Per unit:
// fullmask skip -> 8 scalar mask words (rfl64 -> SALU cursor) -> serial
// sorted scan with 3-record rotation / depth-2 s_load prefetch. No LDS, no
// barriers, no heavy path (R5 WRITE evidence: ~all slabs <=32 candidates).
// ---------------------------------------------------------------------------
__global__ __launch_bounds__(128) void voxelize_kernel(
    const float*              __restrict__ body,
    const unsigned long long* __restrict__ masks,
    const unsigned*           __restrict__ fullmask,
    float*                    __restrict__ out)
{
    const int lane = threadIdx.x & 63;
    const int wid  = __builtin_amdgcn_readfirstlane(
                         (int)((blockIdx.x << 1) | (threadIdx.x >> 6)));
    int       u  = (wid * NUNIT) >> 13;          // * 27648 / 8192
    const int u1 = ((wid + 1) * NUNIT) >> 13;
    if (u >= u1) return;

    int b   = u / NSLAB;
    int rem = u - b * NSLAB;
    int col = rem / 24;
    int sz  = rem - col * 24;

    const int lx = lane >> 3, ly = lane & 7;

    for (; u < u1; ++u) {
        const int sx = col / 12, sy = col - (col / 12) * 12;
        const int ix = sx * 8 + lx;
        const int iy = sy * 8 + ly;
        const float px  = (float)(2*ix + 1 - VWD) / 96.0f;
        const float py  = (float)(2*iy + 1 - VWD) / 96.0f;
        const float pz0 = (float)(8*sz + 1 - VWD) / 96.0f;
        const float pz1 = (float)(8*sz + 3 - VWD) / 96.0f;
        const float pz2 = (float)(8*sz + 5 - VWD) / 96.0f;
        const float pz3 = (float)(8*sz + 7 - VWD) / 96.0f;

        unsigned fnd = 0u;
        do {
            // fully-contained slab: convexity => every voxel inside.
            if ((fullmask[b * 144 + col] >> sz) & 1u) { fnd = 15u; break; }

            const unsigned long long* mp =
                masks + ((size_t)b * NSLAB + col * 24 + sz) * 8;
            unsigned long long W[8];
#pragma unroll
            for (int j = 0; j < 8; ++j) W[j] = rfl64(mp[j]);
            const int total = __popcll(W[0]) + __popcll(W[1]) + __popcll(W[2]) +
                              __popcll(W[3]) + __popcll(W[4]) + __popcll(W[5]) +
                              __popcll(W[6]) + __popcll(W[7]);
            if (total == 0) break;

            const float* bb = body + (size_t)b * NFAC * RECF;
            unsigned long long cm = W[0]; int cwi = 0;
#define ADV(dst)                                                        \
            {                                                           \
                while (cm == 0ull && cwi < 7) { ++cwi; cm = W[cwi]; }   \
                if (cm == 0ull) dst = -1;                               \
                else { int bit_ = (int)__builtin_ctzll(cm);             \
                       cm &= cm - 1ull; dst = (cwi << 6) + bit_; }      \
            }
            int fa, fb, fc;
            ADV(fa);                       // total > 0 => valid
            ADV(fb);
            Rec r0, r1, r2;
            load_rec(r0, bb + (size_t)__builtin_amdgcn_readfirstlane(fa) * RECF);
            load_rec(r1, bb + (size_t)__builtin_amdgcn_readfirstlane(
                                           fb >= 0 ? fb : fa) * RECF);
            // invariant at each LSTEP(RC,RP): RC = record of candidate to
            // test now; fb = index of the NEXT candidate (-1 if none); RP
            // receives the record of the candidate AFTER next (depth-2).
#define LSTEP(RC, RP)                                                   \
            {                                                           \
                ADV(fc);                                                \
                load_rec(RP, bb + (size_t)__builtin_amdgcn_readfirstlane(\
                                      fc >= 0 ? fc : fa) * RECF);       \
                facet_test_reg(RC, px, py, pz0, pz1, pz2, pz3, fnd);    \
                if (__all(fnd == 15u) || fb < 0) break;                 \
                fb = fc;                                                \
            }
            for (;;) { LSTEP(r0, r2) LSTEP(r1, r0) LSTEP(r2, r1) }
#undef LSTEP
#undef ADV
        } while (0);

        float4 v;
        v.x = (fnd & 1u) ? 1.0f : 0.0f;
        v.y = (fnd & 2u) ? 1.0f : 0.0f;
        v.z = (fnd & 4u) ? 1.0f : 0.0f;
        v.w = (fnd & 8u) ? 1.0f : 0.0f;
        *(float4*)&out[(size_t)b*(VWD*VWD*VWD) + (size_t)ix*(VWD*VWD)
                       + iy*VWD + sz*4] = v;

        // increment (b, col, sz) — scalar carry chain
        if (++sz == 24) { sz = 0; if (++col == 144) { col = 0; ++b; } }
    }
}

extern "C" void kernel_launch(void* const* d_in, const int* in_sizes, int n_in,
                              void* d_out, int out_size, void* d_ws, size_t ws_size,
                              hipStream_t stream) {
    const float* vertices = (const float*)d_in[0];   // (8, 2048, 3) f32
    const int*   facets   = (const int*)d_in[1];     // (8, 512, 4) int
    float*       out      = (float*)d_out;           // (8, 96, 96, 96) f32

    // d_ws layout:
    //   cul SoA     26*8*512*4 = 425984   @ 0
    //   body        8*512*16*4 = 262144   @ 425984
    //   masks       8*3456*8*8 = 1769472  @ 688128
    //   fullmask    8*144*4    = 4608     @ 2457600   (end ~2.46 MB)
    float* cul  = (float*)d_ws;
    float* body = (float*)((char*)d_ws + 425984);
    unsigned long long* msk = (unsigned long long*)((char*)d_ws + 688128);
    unsigned* fullmask = (unsigned*)((char*)d_ws + 2457600);

    precompute_kernel<<<NBATCH, 512, 0, stream>>>(vertices, facets, cul, body);
    mask_kernel<<<dim3(144, NBATCH), 512, 0, stream>>>(cul, msk, fullmask);
    voxelize_kernel<<<VOXBLK, 128, 0, stream>>>(body, msk, fullmask, out);
}

// Round 9
// 170.545 us; speedup vs baseline: 1.1225x; 1.1225x over previous
//
#include <hip/hip_runtime.h>

// Match numpy f32 semantics: no FMA contraction anywhere in this TU.
#pragma clang fp contract(off)

#define VWD 96
#define NVERT 2048
#define NFAC 512
#define NBATCH 8
#define NSLAB 3456          // 144 columns x 24 z-slabs of 8x8x4 voxels
#define RECF 16             // floats per facet body record
#define CULC 26             // cull components (SoA)
#define NUNIT (NBATCH * NSLAB)   // 27648 slab-units
#define VOXBLK 4096              // persistent grid: 16 blocks/CU x 256 CU
#define NWAVE (VOXBLK * 2)       // 8192 waves; units strided by NWAVE
#define THEAVY 48                // total>THEAVY -> heavy list (8-wave coop)
#define HGRID 2048               // heavy kernel grid (grid-stride over list)

// SoA cull addressing: component c, batch b, facet f
#define CUL(c, b, f) cul[(size_t)(c) * (NBATCH * NFAC) + (size_t)(b) * NFAC + (f)]

// ---------------------------------------------------------------------------
// Kernel 1: per-batch facet precompute, ordered by |det| descending via a
// ONE-BARRIER rank sort. Body records SIGN-FOLDED: det<0 => negate A,det
// (IEEE negation commutes exactly through mul/add/div).
//   body[b][s][16] : det,v3x,v3y,v3z, A00..A22, dhi, mhi, pad
// Per-plane containment delta D_i = -(M + 2E + 2e-3): slab center passing
// d_i <= D_i for all 4 planes => whole slab definitely inside (convexity;
// plane row and adjugate row are both 2*face-area so |det| cancels in
// barycentric units; degenerate facets cannot pass).
// Also zeroes the heavy-list counter (runs before mask_kernel in-stream).
// ---------------------------------------------------------------------------
__global__ __launch_bounds__(512) void precompute_kernel(
    const float* __restrict__ vertices,
    const int*   __restrict__ facets,
    float*       __restrict__ cul,
    float*       __restrict__ body,
    unsigned*    __restrict__ scnt)
{
    __shared__ unsigned skey[NFAC];
    const int b = blockIdx.x;
    const int j = threadIdx.x;          // one facet per thread
    if (b == 0 && j == 0) scnt[0] = 0u;
    const float* vb = vertices + (size_t)b * NVERT * 3;

    int4 fi = ((const int4*)facets)[b * NFAC + j];
    float x0 = vb[3*fi.x+0], y0 = vb[3*fi.x+1], z0 = vb[3*fi.x+2];
    float x1 = vb[3*fi.y+0], y1 = vb[3*fi.y+1], z1 = vb[3*fi.y+2];
    float x2 = vb[3*fi.z+0], y2 = vb[3*fi.z+1], z2 = vb[3*fi.z+2];
    float x3 = vb[3*fi.w+0], y3 = vb[3*fi.w+1], z3 = vb[3*fi.w+2];
    float a  = x0-x3, bb = x1-x3, c  = x2-x3;
    float d  = y0-y3, e  = y1-y3, f  = y2-y3;
    float g  = z0-z3, h  = z1-z3, ii = z2-z3;
    float A00 = e*ii - f*h,  A01 = c*h  - bb*ii, A02 = bb*f - c*e;
    float A10 = f*g  - d*ii, A11 = a*ii - c*g,   A12 = c*d  - a*f;
    float A20 = d*h  - e*g,  A21 = bb*g - a*h,   A22 = a*e  - bb*d;
    float det = a*(e*ii - f*h) - bb*(d*ii - f*g) + c*(d*h - e*g);
    if (det < 0.0f) {   // sign-fold (exact)
        det = -det;
        A00 = -A00; A01 = -A01; A02 = -A02;
        A10 = -A10; A11 = -A11; A12 = -A12;
        A20 = -A20; A21 = -A21; A22 = -A22;
    }
    unsigned myk = ~__float_as_uint(det);   // ascending key == descending |det|
    skey[j] = myk;
    __syncthreads();

    // rank = #{k : key_k < myk or (key_k == myk and k < j)}  -> unique slot
    int rank = 0;
    const uint4* sk4 = (const uint4*)skey;
    for (int k0 = 0; k0 < NFAC; k0 += 4) {
        uint4 kk = sk4[k0 >> 2];
        rank += (kk.x < myk) + ((kk.x == myk) & (k0 + 0 < j));
        rank += (kk.y < myk) + ((kk.y == myk) & (k0 + 1 < j));
        rank += (kk.z < myk) + ((kk.z == myk) & (k0 + 2 < j));
        rank += (kk.w < myk) + ((kk.w == myk) & (k0 + 3 < j));
    }

    CUL(0, b, rank) = fminf(fminf(x0,x1),fminf(x2,x3)) - 1e-4f;
    CUL(1, b, rank) = fminf(fminf(y0,y1),fminf(y2,y3)) - 1e-4f;
    CUL(2, b, rank) = fminf(fminf(z0,z1),fminf(z2,z3)) - 1e-4f;
    CUL(3, b, rank) = fmaxf(fmaxf(x0,x1),fmaxf(x2,x3)) + 1e-4f;
    CUL(4, b, rank) = fmaxf(fmaxf(y0,y1),fmaxf(y2,y3)) + 1e-4f;
    CUL(5, b, rank) = fmaxf(fmaxf(z0,z1),fmaxf(z2,z3)) + 1e-4f;

    // 4 outward face planes, margin-inflated, slab half-extents folded:
    // overlap test:      dot(n, slab_center) - rhs <= 0   (conservative)
    // containment test:  dot(n, slab_center) - rhs <= D   (definite)
    const float HX = 7.0f/96.0f, HZ = 3.0f/96.0f;
    auto plane = [&](float pax, float pay, float paz,
                     float pbx, float pby, float pbz,
                     float pcx, float pcy, float pcz,
                     float pox, float poy, float poz, int base, int pi) {
        float e1x = pbx-pax, e1y = pby-pay, e1z = pbz-paz;
        float e2x = pcx-pax, e2y = pcy-pay, e2z = pcz-paz;
        float nx = e1y*e2z - e1z*e2y;
        float ny = e1z*e2x - e1x*e2z;
        float nz = e1x*e2y - e1y*e2x;
        float sdot = nx*(pox-pax) + ny*(poy-pay) + nz*(poz-paz);
        if (sdot > 0.0f) { nx=-nx; ny=-ny; nz=-nz; sdot=-sdot; }
        float dpl = nx*pax + ny*pay + nz*paz;
        float n1s = fabsf(nx)+fabsf(ny)+fabsf(nz);
        float M = 1e-4f*(-sdot) + 1e-4f*n1s + 1e-4f;
        float E = fabsf(nx)*HX + fabsf(ny)*HX + fabsf(nz)*HZ;
        float rhs = dpl + M + E;
        CUL(base+0, b, rank) = nx;
        CUL(base+1, b, rank) = ny;
        CUL(base+2, b, rank) = nz;
        CUL(base+3, b, rank) = rhs;
        CUL(22+pi, b, rank) = -(M + 2.0f*E + 2e-3f);   // containment delta
    };
    plane(x1,y1,z1, x2,y2,z2, x3,y3,z3, x0,y0,z0, 6, 0);    // opposite v0
    plane(x0,y0,z0, x2,y2,z2, x3,y3,z3, x1,y1,z1, 10, 1);   // opposite v1
    plane(x0,y0,z0, x1,y1,z1, x3,y3,z3, x2,y2,z2, 14, 2);   // opposite v2
    plane(x0,y0,z0, x1,y1,z1, x2,y2,z2, x3,y3,z3, 18, 3);   // opposite v3

    float* bo = body + ((size_t)b * NFAC + rank) * RECF;
    bo[0]  = det; bo[1]  = x3;  bo[2]  = y3;  bo[3]  = z3;
    bo[4]  = A00; bo[5]  = A01; bo[6]  = A02; bo[7]  = A10;
    bo[8]  = A11; bo[9]  = A12; bo[10] = A20; bo[11] = A21;
    bo[12] = A22;
    bo[13] = det * (1.0f - 1e-5f) - 1e-25f;   // dhi
    bo[14] = det * (1.0f + 1e-5f) + 1e-25f;   // mhi
    bo[15] = 0.0f;
}

// ---------------------------------------------------------------------------
// Kernel 2: per-slab 512-bit facet mask + "fully contained" flag + COMPACT
// HEAVY LIST (total>THEAVY, not full). One block per (batch, column);
// facet-per-lane, cull record loaded ONCE (SoA, coalesced); 24 z-slabs via
// incremental plane dots. Heavy append is lane-aggregated: ONE atomicAdd per
// block that has any heavy slab (<=1152 total — R1 lesson: thousands of
// same-address atomics with dependent reads serialize the chip).
// ---------------------------------------------------------------------------
__global__ __launch_bounds__(512) void mask_kernel(
    const float* __restrict__ cul,
    unsigned long long* __restrict__ masks,
    unsigned* __restrict__ fullmask,
    unsigned* __restrict__ scnt,
    unsigned short* __restrict__ hlist)
{
    __shared__ unsigned fullbits;
    __shared__ unsigned wcnt[8][24];
    const int col = blockIdx.x;           // 0..143 = sx*12+sy
    const int b   = blockIdx.y;
    const int f   = threadIdx.x;          // facet (sorted order)
    const int w   = threadIdx.x >> 6;
    if (threadIdx.x == 0) fullbits = 0u;
    __syncthreads();
    float bminx=CUL(0,b,f), bminy=CUL(1,b,f), bminz=CUL(2,b,f);
    float bmaxx=CUL(3,b,f), bmaxy=CUL(4,b,f), bmaxz=CUL(5,b,f);
    float n0x=CUL(6,b,f),  n0y=CUL(7,b,f),  n0z=CUL(8,b,f),  r0=CUL(9,b,f);
    float n1x=CUL(10,b,f), n1y=CUL(11,b,f), n1z=CUL(12,b,f), r1=CUL(13,b,f);
    float n2x=CUL(14,b,f), n2y=CUL(15,b,f), n2z=CUL(16,b,f), r2=CUL(17,b,f);
    float n3x=CUL(18,b,f), n3y=CUL(19,b,f), n3z=CUL(20,b,f), r3=CUL(21,b,f);
    float D0=CUL(22,b,f), D1=CUL(23,b,f), D2=CUL(24,b,f), D3=CUL(25,b,f);

    const int sx = col / 12, sy = col % 12;
    const float cx = (float)(16*sx + 8 - VWD) / 96.0f;
    const float cy = (float)(16*sy + 8 - VWD) / 96.0f;
    const float colminx = (float)(16*sx + 1  - VWD) / 96.0f;
    const float colmaxx = (float)(16*sx + 15 - VWD) / 96.0f;
    const float colminy = (float)(16*sy + 1  - VWD) / 96.0f;
    const float colmaxy = (float)(16*sy + 15 - VWD) / 96.0f;
    const bool ovxy = (bminx <= colmaxx) & (bmaxx >= colminx) &
                      (bminy <= colmaxy) & (bmaxy >= colminy);

    const float cz0   = (float)(4 - VWD) / 96.0f;   // z-center of slab sz=0
    const float stepc = 8.0f / 96.0f;
    float d0 = n0x*cx + n0y*cy + n0z*cz0 - r0;  float s0 = n0z*stepc;
    float d1 = n1x*cx + n1y*cy + n1z*cz0 - r1;  float s1 = n1z*stepc;
    float d2 = n2x*cx + n2y*cy + n2z*cz0 - r2;  float s2 = n2z*stepc;
    float d3 = n3x*cx + n3y*cy + n3z*cz0 - r3;  float s3 = n3z*stepc;
    float zlo = (float)(1 - VWD) / 96.0f;
    float zhi = (float)(7 - VWD) / 96.0f;

    unsigned fullw = 0u;
    unsigned long long* mp = masks + ((size_t)b * NSLAB + (size_t)col * 24) * 8 + w;
#pragma unroll 4
    for (int sz = 0; sz < 24; ++sz) {
        bool ov = ovxy & (bminz <= zhi) & (bmaxz >= zlo) &
                  (d0 <= 0.0f) & (d1 <= 0.0f) & (d2 <= 0.0f) & (d3 <= 0.0f);
        bool fullv = (d0 <= D0) & (d1 <= D1) & (d2 <= D2) & (d3 <= D3);
        unsigned long long bal = __ballot((int)ov);
        if ((threadIdx.x & 63) == 0) {
            mp[(size_t)sz * 8] = bal;
            wcnt[w][sz] = (unsigned)__popcll(bal);
        }
        if (__ballot((int)fullv) != 0ull) fullw |= (1u << sz);
        d0 += s0; d1 += s1; d2 += s2; d3 += s3;
        zlo += stepc; zhi += stepc;
    }
    if ((threadIdx.x & 63) == 0 && fullw) atomicOr(&fullbits, fullw);
    __syncthreads();
    if (threadIdx.x == 0) fullmask[b * 144 + col] = fullbits;

    // heavy-slab append (wave 0, lanes 0..23 = sz)
    if (threadIdx.x < 24) {
        const int sz = threadIdx.x;
        unsigned tot = wcnt[0][sz] + wcnt[1][sz] + wcnt[2][sz] + wcnt[3][sz] +
                       wcnt[4][sz] + wcnt[5][sz] + wcnt[6][sz] + wcnt[7][sz];
        bool heavy = (tot > THEAVY) && !((fullbits >> sz) & 1u);
        unsigned long long bal = __ballot((int)heavy);
        if (threadIdx.x == 0) {
            unsigned hm = (unsigned)bal & 0xFFFFFFu;
            int n = __popc(hm);
            if (n) {
                unsigned base = atomicAdd(scnt, (unsigned)n);
                while (hm) {
                    int s = __builtin_ctz(hm); hm &= hm - 1u;
                    hlist[base++] = (unsigned short)(b * NSLAB + col * 24 + s);
                }
            }
        }
    }
}

// Facet body record in wave-uniform (SGPR) registers.
struct Rec {
    float det, v3x, v3y, v3z;
    float A00, A01, A02, A10, A11, A12, A20, A21, A22;
    float dhi, mhi;
};

__device__ __forceinline__ void load_rec(Rec& r, const float* __restrict__ bo)
{
    float4 q0 = *(const float4*)(bo + 0);
    float4 q1 = *(const float4*)(bo + 4);
    float4 q2 = *(const float4*)(bo + 8);
    float4 q3 = *(const float4*)(bo + 12);
    r.det = q0.x; r.v3x = q0.y; r.v3y = q0.z; r.v3z = q0.w;
    r.A00 = q1.x; r.A01 = q1.y; r.A02 = q1.z; r.A10 = q1.w;
    r.A11 = q2.x; r.A12 = q2.y; r.A20 = q2.z; r.A21 = q2.w;
    r.A22 = q3.x; r.dhi = q3.y; r.mhi = q3.z;
}

// Scalarize a wave-uniform 64-bit value (keeps the candidate cursor on SALU
// and record loads as s_load; R5 lesson: losing this ballooned VGPR 20->52).
__device__ __forceinline__ unsigned long long rfl64(unsigned long long v)
{
    unsigned lo = __builtin_amdgcn_readfirstlane((unsigned)v);
    unsigned hi = __builtin_amdgcn_readfirstlane((unsigned)(v >> 32));
    return ((unsigned long long)hi << 32) | lo;
}

// Position of the (r+1)-th set bit of m (r 0-based, r < popcll(m)).
__device__ __forceinline__ int nth_set_bit(unsigned long long m, int r)
{
    int pos = 0;
    unsigned c;
    c = (unsigned)__popcll(m & 0xFFFFFFFFull);
    if ((unsigned)r >= c) { r -= c; m >>= 32; pos += 32; }
    c = (unsigned)__popcll(m & 0xFFFFull);
    if ((unsigned)r >= c) { r -= c; m >>= 16; pos += 16; }
    c = (unsigned)__popcll(m & 0xFFull);
    if ((unsigned)r >= c) { r -= c; m >>= 8;  pos += 8; }
    c = (unsigned)__popcll(m & 0xFull);
    if ((unsigned)r >= c) { r -= c; m >>= 4;  pos += 4; }
    c = (unsigned)__popcll(m & 0x3ull);
    if ((unsigned)r >= c) { r -= c; m >>= 2;  pos += 2; }
    c = (unsigned)__popcll(m & 0x1ull);
    if ((unsigned)r >= c) { r -= c; m >>= 1;  pos += 1; }
    return pos;
}

// ---------------------------------------------------------------------------
// Per-candidate exact test on a register-resident record. Numerators
// bit-identical to ref; exact l_i>=0 sign test; det-relative shell on the
// sum; ONE __any branch per candidate guards the (rare) exact-division path.
// ---------------------------------------------------------------------------
__device__ __forceinline__ void facet_test_reg(
    const Rec& rr,
    float px, float py, float pz0, float pz1, float pz2, float pz3,
    unsigned& fnd)
{
    float dx = px - rr.v3x, dy = py - rr.v3y;
    // ref-exact partials (left-assoc, contract off)
    float p0 = rr.A00*dx + rr.A01*dy;
    float p1 = rr.A10*dx + rr.A11*dy;
    float p2 = rr.A20*dx + rr.A21*dy;
    float dzk0 = pz0 - rr.v3z, dzk1 = pz1 - rr.v3z;
    float dzk2 = pz2 - rr.v3z, dzk3 = pz3 - rr.v3z;
    unsigned need = 0u;   // bit k: lane in shell, must run exact path
#pragma unroll
    for (int k = 0; k < 4; ++k) {
        float dzk = (k == 0) ? dzk0 : (k == 1) ? dzk1
                  : (k == 2) ? dzk2 : dzk3;
        float n0 = p0 + rr.A02*dzk;
        float n1 = p1 + rr.A12*dzk;
        float n2 = p2 + rr.A22*dzk;
        float sm = (n0 + n1) + n2;
        float mn = fminf(fminf(n0, n1), n2);   // v_min3_f32
        bool ge0 = (mn >= 0.0f);               // EXACT l_i>=0 test
        bool def = ge0 & (sm <= rr.dhi);
        bool may = ge0 & (sm <= rr.mhi);
        if (may & !def & !((fnd >> k) & 1u)) need |= (1u << k);
        if (def) fnd |= (1u << k);
    }
    if (__any(need != 0u)) {
#pragma unroll
        for (int k = 0; k < 4; ++k) {
            float dzk = (k == 0) ? dzk0 : (k == 1) ? dzk1
                      : (k == 2) ? dzk2 : dzk3;
            float n0 = p0 + rr.A02*dzk;
            float n1 = p1 + rr.A12*dzk;
            float n2 = p2 + rr.A22*dzk;
            float l0 = n0 / rr.det;
            float l1 = n1 / rr.det;
            float l2 = n2 / rr.det;
            float l3 = 1.0f - ((l0 + l1) + l2);
            bool inside = (l0 >= 0.0f) & (l0 <= 1.0f) &
                          (l1 >= 0.0f) & (l1 <= 1.0f) &
                          (l2 >= 0.0f) & (l2 <= 1.0f) &
                          (l3 >= 0.0f) & (l3 <= 1.0f);
            if (((need >> k) & 1u) & inside) fnd |= (1u << k);
        }
    }
}

// ---------------------------------------------------------------------------
// Kernel 3 (LIGHT, persistent+STRIDED): 4096 blocks x 128 thr = 8192 waves,
// one CP pass (R6 lesson: tiny-block dispatches are CP-rate bound). Units
// strided by 8192 (R7 lesson: CONTIGUOUS chunks cluster heavy boundary slabs
// into one wave -> 110us serial tail; striding decorrelates). Per unit:
// fullmask skip -> 8 scalar mask words -> total; total>THEAVY -> heavy kernel
// owns it (skip); else serial sorted scan, 3-record rotation, depth-2 s_load
// prefetch. No LDS, no barriers.
// ---------------------------------------------------------------------------
__global__ __launch_bounds__(128) void voxelize_light(
    const float*              __restrict__ body,
    const unsigned long long* __restrict__ masks,
    const unsigned*           __restrict__ fullmask,
    float*                    __restrict__ out)
{
    const int lane = threadIdx.x & 63;
    const int wid  = __builtin_amdgcn_readfirstlane(
                         (int)((blockIdx.x << 1) | (threadIdx.x >> 6)));
    const int lx = lane >> 3, ly = lane & 7;

    for (int u = wid; u < NUNIT; u += NWAVE) {
        const int b   = u / NSLAB;
        const int rem = u - b * NSLAB;
        const int col = rem / 24;
        const int sz  = rem - col * 24;
        const int sx = col / 12, sy = col - (col / 12) * 12;
        const int ix = sx * 8 + lx;
        const int iy = sy * 8 + ly;
        const float px  = (float)(2*ix + 1 - VWD) / 96.0f;
        const float py  = (float)(2*iy + 1 - VWD) / 96.0f;
        const float pz0 = (float)(8*sz + 1 - VWD) / 96.0f;
        const float pz1 = (float)(8*sz + 3 - VWD) / 96.0f;
        const float pz2 = (float)(8*sz + 5 - VWD) / 96.0f;
        const float pz3 = (float)(8*sz + 7 - VWD) / 96.0f;

        unsigned fnd = 0u;
        bool skip = false;
        do {
            // fully-contained slab: convexity => every voxel inside.
            if ((fullmask[b * 144 + col] >> sz) & 1u) { fnd = 15u; break; }

            const unsigned long long* mp =
                masks + ((size_t)b * NSLAB + col * 24 + sz) * 8;
            unsigned long long W[8];
#pragma unroll
            for (int j = 0; j < 8; ++j) W[j] = rfl64(mp[j]);
            const int total = __popcll(W[0]) + __popcll(W[1]) + __popcll(W[2]) +
                              __popcll(W[3]) + __popcll(W[4]) + __popcll(W[5]) +
                              __popcll(W[6]) + __popcll(W[7]);
            if (total > THEAVY) { skip = true; break; }   // heavy owns it
            if (total == 0) break;

            const float* bb = body + (size_t)b * NFAC * RECF;
            unsigned long long cm = W[0]; int cwi = 0;
#define ADV(dst)                                                        \
            {                                                           \
                while (cm == 0ull && cwi < 7) { ++cwi; cm = W[cwi]; }   \
                if (cm == 0ull) dst = -1;                               \
                else { int bit_ = (int)__builtin_ctzll(cm);             \
                       cm &= cm - 1ull; dst = (cwi << 6) + bit_; }      \
            }
            int fa, fb, fc;
            ADV(fa);                       // total > 0 => valid
            ADV(fb);
            Rec r0, r1, r2;
            load_rec(r0, bb + (size_t)__builtin_amdgcn_readfirstlane(fa) * RECF);
            load_rec(r1, bb + (size_t)__builtin_amdgcn_readfirstlane(
                                           fb >= 0 ? fb : fa) * RECF);
#define LSTEP(RC, RP)                                                   \
            {                                                           \
                ADV(fc);                                                \
                load_rec(RP, bb + (size_t)__builtin_amdgcn_readfirstlane(\
                                      fc >= 0 ? fc : fa) * RECF);       \
                facet_test_reg(RC, px, py, pz0, pz1, pz2, pz3, fnd);    \
                if (__all(fnd == 15u) || fb < 0) break;                 \
                fb = fc;                                                \
            }
            for (;;) { LSTEP(r0, r2) LSTEP(r1, r0) LSTEP(r2, r1) }
#undef LSTEP
#undef ADV
        } while (0);

        if (!skip) {
            float4 v;
            v.x = (fnd & 1u) ? 1.0f : 0.0f;
            v.y = (fnd & 2u) ? 1.0f : 0.0f;
            v.z = (fnd & 4u) ? 1.0f : 0.0f;
            v.w = (fnd & 8u) ? 1.0f : 0.0f;
            *(float4*)&out[(size_t)b*(VWD*VWD*VWD) + (size_t)ix*(VWD*VWD)
                           + iy*VWD + sz*4] = v;
        }
    }
}

// ---------------------------------------------------------------------------
// Kernel 4 (HEAVY, compact list): HGRID blocks x 512 thr grid-striding over
// the heavy list only (blocks past the count read one scalar and exit).
// Per slab: 8 waves build the LDS candidate list (wave w extracts word w,
// offsets from local popcounts), then stride-8 scan with record prefetch and
// stale-OK LDS per-lane union for cross-wave early exit. Pole: 512/8 x ~190
// cyc ~ 5us.
// ---------------------------------------------------------------------------
__global__ __launch_bounds__(512) void voxelize_heavy(
    const float*              __restrict__ body,
    const unsigned long long* __restrict__ masks,
    float*                    __restrict__ out,
    const unsigned*           __restrict__ scnt,
    const unsigned short*     __restrict__ hlist)
{
    __shared__ unsigned short lst[NFAC];
    __shared__ unsigned fl[64];
    const unsigned cnt = *scnt;
    const int wave = threadIdx.x >> 6;
    const int lane = threadIdx.x & 63;

    for (unsigned e = blockIdx.x; e < cnt; e += gridDim.x) {
        __syncthreads();                        // lst/fl reuse guard
        if (threadIdx.x < 64) fl[threadIdx.x] = 0u;

        const int v    = (int)hlist[e];
        const int b    = v / NSLAB;
        const int slab = v - b * NSLAB;
        const int col  = slab / 24;
        const int sz   = slab - col * 24;
        const int sx = col / 12, sy = col - (col / 12) * 12;
        const int ix = sx * 8 + (lane >> 3);
        const int iy = sy * 8 + (lane & 7);
        const float px  = (float)(2*ix + 1 - VWD) / 96.0f;
        const float py  = (float)(2*iy + 1 - VWD) / 96.0f;
        const float pz0 = (float)(8*sz + 1 - VWD) / 96.0f;
        const float pz1 = (float)(8*sz + 3 - VWD) / 96.0f;
        const float pz2 = (float)(8*sz + 5 - VWD) / 96.0f;
        const float pz3 = (float)(8*sz + 7 - VWD) / 96.0f;

        const unsigned long long* mp =
            masks + ((size_t)b * NSLAB + slab) * 8;
        unsigned long long W[8];
#pragma unroll
        for (int j = 0; j < 8; ++j) W[j] = rfl64(mp[j]);
        const unsigned long long mw = W[wave];
        const int cw = __popcll(mw);
        int off = 0, total = 0;
#pragma unroll
        for (int j = 0; j < 8; ++j) {
            int cj = __popcll(W[j]);
            if (j < wave) off += cj;
            total += cj;
        }
        if (lane < cw)
            lst[off + lane] = (unsigned short)((wave << 6) + nth_set_bit(mw, lane));
        __syncthreads();

        const float* bb = body + (size_t)b * NFAC * RECF;
        {
            unsigned fnd = 0u, pub = 0u;
            int i = wave;                       // total > THEAVY >= 8
            int f0 = __builtin_amdgcn_readfirstlane((int)lst[i]);
            Rec rc; load_rec(rc, bb + (size_t)f0 * RECF);
            for (;;) {
                int inext = i + 8;
                int fn = __builtin_amdgcn_readfirstlane(
                             (int)lst[inext < total ? inext : i]);
                Rec rn; load_rec(rn, bb + (size_t)fn * RECF);
                unsigned flv = fl[lane];        // stale union (monotonic OR)
                facet_test_reg(rc, px, py, pz0, pz1, pz2, pz3, fnd);
                fnd |= flv;
                if (fnd != pub) { atomicOr(&fl[lane], fnd); pub = fnd; }
                if (__all(fnd == 15u) || inext >= total) break;
                i = inext; rc = rn;
            }
            if (fnd != pub) atomicOr(&fl[lane], fnd);
        }
        __syncthreads();
        if (threadIdx.x < 64) {
            unsigned u = fl[threadIdx.x];
            float4 rv;
            rv.x = (u & 1u) ? 1.0f : 0.0f;
            rv.y = (u & 2u) ? 1.0f : 0.0f;
            rv.z = (u & 4u) ? 1.0f : 0.0f;
            rv.w = (u & 8u) ? 1.0f : 0.0f;
            *(float4*)&out[(size_t)b*(VWD*VWD*VWD) + (size_t)ix*(VWD*VWD)
                           + iy*VWD + sz*4] = rv;
        }
    }
}

extern "C" void kernel_launch(void* const* d_in, const int* in_sizes, int n_in,
                              void* d_out, int out_size, void* d_ws, size_t ws_size,
                              hipStream_t stream) {
    const float* vertices = (const float*)d_in[0];   // (8, 2048, 3) f32
    const int*   facets   = (const int*)d_in[1];     // (8, 512, 4) int
    float*       out      = (float*)d_out;           // (8, 96, 96, 96) f32

    // d_ws layout:
    //   cul SoA     26*8*512*4 = 425984   @ 0
    //   body        8*512*16*4 = 262144   @ 425984
    //   masks       8*3456*8*8 = 1769472  @ 688128
    //   fullmask    8*144*4    = 4608     @ 2457600
    //   scnt        4 (padded 64)         @ 2462208
    //   hlist       27648*2    = 55296    @ 2462272   (end ~2.52 MB)
    float* cul  = (float*)d_ws;
    float* body = (float*)((char*)d_ws + 425984);
    unsigned long long* msk = (unsigned long long*)((char*)d_ws + 688128);
    unsigned* fullmask = (unsigned*)((char*)d_ws + 2457600);
    unsigned* scnt     = (unsigned*)((char*)d_ws + 2462208);
    unsigned short* hlist = (unsigned short*)((char*)d_ws + 2462272);

    precompute_kernel<<<NBATCH, 512, 0, stream>>>(vertices, facets, cul, body, scnt);
    mask_kernel<<<dim3(144, NBATCH), 512, 0, stream>>>(cul, msk, fullmask, scnt, hlist);
    voxelize_light<<<VOXBLK, 128, 0, stream>>>(body, msk, fullmask, out);
    voxelize_heavy<<<HGRID, 512, 0, stream>>>(body, msk, out, scnt, hlist);
}